// Round 6
// baseline (461.121 us; speedup 1.0000x reference)
//
#include <hip/hip_runtime.h>
#include <hip/hip_bf16.h>

#define EPS 1e-5f

typedef __bf16 bf16x8 __attribute__((ext_vector_type(8)));
typedef float f32x4 __attribute__((ext_vector_type(4)));

// lds dest is WAVE-UNIFORM base; HW scatters lane i -> base + 16*i bytes
__device__ __forceinline__ void async_load16(const __bf16* g, __bf16* lds_base) {
  __builtin_amdgcn_global_load_lds(
      (const __attribute__((address_space(1))) unsigned int*)g,
      (__attribute__((address_space(3))) unsigned int*)lds_base, 16, 0, 0);
}

// ---- workspace layout (total 82,283,520 B; ws_size >= this, proven R0) -----
// xpad  : [16][30][30][512] bf16 @ 0          (14,745,600 B)
// t1pad : [16][58][58][256] bf16 @ 14,745,600 (27,557,888 B)
// wb    : [25][512][512] bf16    @ 42,303,488 (13,107,200 B)
// w2b   : [9][256][256] bf16     @ 55,410,688 (1,179,648 B)
// scb   : [16][56][56][256] bf16 @ 56,590,336 (25,690,112 B)
// biasA : 512 f32                @ 82,280,448
// bias2 : 256 f32                @ 82,282,496

// A-LDS swizzle (row = 64 elems = 8 chunks of 16B):
//   LDS[row][slot] holds global k-chunk slot^(row&7); staging lane i fetches
//   global chunk (i&7)^((i>>3)&7); reader: slot = chunk ^ (fr&7). Quarter-wave
//   covers all 8 bank groups 2-way -> conflict-free (m136).

// ---------------- zero xpad + t1pad (contiguous span) -----------------------
__global__ void zero_kernel(uint4* __restrict__ p, int n4) {
  int i = blockIdx.x * 256 + threadIdx.x;
  if (i < n4) p[i] = (uint4){0u, 0u, 0u, 0u};
}

// ---------------- weight prep: fold BN scale, bf16 [tap][co][ci], coalesced -
__global__ void prep_kernel(const float* __restrict__ w1, const float* __restrict__ g1,
                            const float* __restrict__ b1, const float* __restrict__ m1,
                            const float* __restrict__ v1,
                            const float* __restrict__ wsc, const float* __restrict__ gs,
                            const float* __restrict__ bs, const float* __restrict__ ms,
                            const float* __restrict__ vs,
                            const float* __restrict__ w2, const float* __restrict__ g2,
                            const float* __restrict__ b2, const float* __restrict__ m2,
                            const float* __restrict__ v2,
                            __bf16* __restrict__ wb, __bf16* __restrict__ w2b,
                            float* __restrict__ biasA, float* __restrict__ bias2) {
  int tid = blockIdx.x * 256 + threadIdx.x;
  if (tid < 409600) {                        // 25 taps * 256 co * 64 ci-groups
    int ci0 = tid & 63;
    int rest = tid >> 6;                     // < 6400
    int co = rest & 255;
    int t = rest >> 8;                       // < 25
    float s1 = g1[co] * rsqrtf(v1[co] + EPS);
    float ss = gs[co] * rsqrtf(vs[co] + EPS);
    const float* p1 = w1 + (co * 512 + ci0 * 8) * 25 + t;
    const float* ps = wsc + (co * 512 + ci0 * 8) * 25 + t;
    bf16x8 a, s;
#pragma unroll
    for (int e = 0; e < 8; ++e) {
      a[e] = (__bf16)(p1[e * 25] * s1);
      s[e] = (__bf16)(ps[e * 25] * ss);
    }
    *(bf16x8*)(wb + (t * 512 + co) * 512 + ci0 * 8) = a;
    *(bf16x8*)(wb + (t * 512 + 256 + co) * 512 + ci0 * 8) = s;
  } else if (tid < 483328) {                 // 9 taps * 256 co * 32 ci-groups
    int t2 = tid - 409600;
    int ci0 = t2 & 31;
    int rest = t2 >> 5;                      // < 2304
    int co = rest & 255;
    int t = rest >> 8;                       // < 9
    float s2 = g2[co] * rsqrtf(v2[co] + EPS);
    const float* p2 = w2 + (co * 256 + ci0 * 8) * 9 + t;
    bf16x8 a;
#pragma unroll
    for (int e = 0; e < 8; ++e) a[e] = (__bf16)(p2[e * 9] * s2);
    *(bf16x8*)(w2b + (t * 256 + co) * 256 + ci0 * 8) = a;
  } else if (tid < 484096) {
    int c = tid - 483328;
    if (c < 256)      biasA[c] = b1[c] - m1[c] * (g1[c] * rsqrtf(v1[c] + EPS));
    else if (c < 512) biasA[c] = bs[c - 256] - ms[c - 256] * (gs[c - 256] * rsqrtf(vs[c - 256] + EPS));
    else              bias2[c - 512] = b2[c - 512] - m2[c - 512] * (g2[c - 512] * rsqrtf(v2[c - 512] + EPS));
  }
}

// ------- x (NCHW f32) -> xpad (padded NHWC bf16 [16][30][30][512]) ----------
__global__ void transpose_kernel(const float* __restrict__ x, __bf16* __restrict__ xpad) {
  __shared__ __bf16 tile[64 * 65];
  const int hw0 = blockIdx.x * 64;
  const int ci0 = blockIdx.y * 64;
  const int b = blockIdx.z;
  const int tid = threadIdx.x;
#pragma unroll
  for (int it = 0; it < 16; ++it) {
    int idx = tid + 256 * it;
    int row = idx >> 6, col = idx & 63;
    int hw = hw0 + col;
    float v = (hw < 784) ? x[(b * 512 + ci0 + row) * 784 + hw] : 0.0f;
    tile[row * 65 + col] = (__bf16)v;
  }
  __syncthreads();
#pragma unroll
  for (int it = 0; it < 16; ++it) {
    int idx = tid + 256 * it;
    int orow = idx >> 6, ocol = idx & 63;
    int hw = hw0 + orow;
    if (hw < 784) {
      int h = hw / 28, w = hw % 28;
      xpad[((b * 30 + 1 + h) * 30 + 1 + w) * 512 + ci0 + ocol] = tile[ocol * 65 + orow];
    }
  }
}

// ---------------- Kernel A: conv1 + shortcut conv (parity-decomposed) -------
// Per q=(py,px): GEMM M=12544, N=512. Block tile 128(M)x256(N); ntile 0 -> w1
// output (t1pad), ntile 1 -> wsc output (scb). Wave = full M x 64 N (8x4
// frags). A double-buffered through LDS (16KB x2); B direct global->VGPR.
__global__ __launch_bounds__(256, 2) void convA_kernel(
    const __bf16* __restrict__ xpad, const __bf16* __restrict__ wb,
    const float* __restrict__ biasA, __bf16* __restrict__ t1pad,
    __bf16* __restrict__ scb) {
  __shared__ alignas(16) __bf16 lA[2][128 * 64];
  const int tid = threadIdx.x;
  const int lane = tid & 63, wv = tid >> 6;
  const int mtile = blockIdx.x, ntile = blockIdx.y, q = blockIdx.z;
  const int py = q >> 1, px = q & 1;
  const int W = (py ? 2 : 3) * (px ? 2 : 3) * 8;   // windows (taps * 512/64)

  // A staging: wave wv covers rows wv*32..+31; 4 insts of 8 rows each
  const int lrow = lane >> 3;
  const int g = ((lane & 7) ^ lrow) * 8;
  int aoffs[4];
#pragma unroll
  for (int j = 0; j < 4; ++j) {
    int m = mtile * 128 + wv * 32 + j * 8 + lrow;
    int b = m / 784, r = m % 784, hy = r / 28, hx = r % 28;
    aoffs[j] = ((b * 30 + 1 + hy) * 30 + (1 + hx)) * 512 + g;
  }

  const int wn = wv * 64;
  const int fr = lane & 15, kh = lane >> 4;
  const int sw = fr & 7;
  const __bf16* bbase = wb + (ntile * 256 + wn + fr) * 512 + kh * 8;

  f32x4 acc[8][4];
#pragma unroll
  for (int f = 0; f < 8; f++)
#pragma unroll
    for (int n = 0; n < 4; n++) acc[f][n] = (f32x4){0.f, 0.f, 0.f, 0.f};

  // window w -> (tap, k0); tap -> (ty,tx) with tx fastest, ntx = px?2:3
  auto decode = [&](int w, int& adelta, int& woff, int& k0) {
    int tap = w >> 3;
    k0 = (w & 7) << 6;
    int ty, tx;
    if (px) { ty = tap >> 1; tx = tap & 1; }
    else    { ty = (tap >= 6) ? 2 : ((tap >= 3) ? 1 : 0); tx = tap - ty * 3; }
    int dy = ty - 1 + py, dx = tx - 1 + px;
    int ky = 2 * ty + py, kx = 2 * tx + px;
    adelta = (dy * 30 + dx) * 512;
    woff = (ky * 5 + kx) * 262144;
  };
  auto stage = [&](int adelta, int k0, int buf) {
    __bf16* dst = &lA[buf][wv * 2048];
#pragma unroll
    for (int j = 0; j < 4; ++j)
      async_load16(xpad + (aoffs[j] + adelta + k0), dst + j * 512);
  };

  int adelta, woff, k0;
  decode(0, adelta, woff, k0);
  stage(adelta, k0, 0);
  __syncthreads();
  for (int w = 0; w < W; ++w) {
    const int buf = w & 1;
    const int cwoff = woff, ck0 = k0;
    if (w + 1 < W) {                      // prefetch next A tile into other buf
      decode(w + 1, adelta, woff, k0);
      stage(adelta, k0, buf ^ 1);
    }
    const __bf16* bp = bbase + cwoff + ck0;
#pragma unroll
    for (int kk = 0; kk < 2; ++kk) {
      bf16x8 bfr[4], af[8];
#pragma unroll
      for (int n = 0; n < 4; ++n)
        bfr[n] = *(const bf16x8*)(bp + n * 16 * 512 + kk * 32);
#pragma unroll
      for (int f = 0; f < 8; ++f)
        af[f] = *(const bf16x8*)(&lA[buf][(f * 16 + fr) * 64 + (((kk * 4 + kh) ^ sw) * 8)]);
#pragma unroll
      for (int f = 0; f < 8; ++f)
#pragma unroll
        for (int n = 0; n < 4; ++n)
          acc[f][n] = __builtin_amdgcn_mfma_f32_16x16x32_bf16(af[f], bfr[n], acc[f][n], 0, 0, 0);
    }
    __syncthreads();                      // drains next-stage vmcnt post-compute
  }

  // epilogue: C/D layout col(n)=fr, row(m)=kh*4+reg
  float bv[4];
#pragma unroll
  for (int n = 0; n < 4; ++n) bv[n] = biasA[ntile * 256 + wn + n * 16 + fr];
  if (ntile == 0) {
#pragma unroll
    for (int f = 0; f < 8; ++f)
#pragma unroll
      for (int r = 0; r < 4; ++r) {
        int m = mtile * 128 + f * 16 + kh * 4 + r;
        int b = m / 784, rr = m % 784, hy = rr / 28, hx = rr % 28;
        int ob = ((b * 58 + 1 + 2 * hy + py) * 58 + (1 + 2 * hx + px)) * 256 + wn + fr;
#pragma unroll
        for (int n = 0; n < 4; ++n)
          t1pad[ob + n * 16] = (__bf16)fmaxf(acc[f][n][r] + bv[n], 0.0f);
      }
  } else {
#pragma unroll
    for (int f = 0; f < 8; ++f)
#pragma unroll
      for (int r = 0; r < 4; ++r) {
        int m = mtile * 128 + f * 16 + kh * 4 + r;
        int b = m / 784, rr = m % 784, hy = rr / 28, hx = rr % 28;
        int ob = ((b * 56 + 2 * hy + py) * 56 + 2 * hx + px) * 256 + wn + fr;
#pragma unroll
        for (int n = 0; n < 4; ++n)
          scb[ob + n * 16] = (__bf16)(acc[f][n][r] + bv[n]);
      }
  }
}

// ---------------- Kernel B: 3x3 conv on t1, + bias2 + scb, relu -> NCHW out -
// GEMM: M=50176, N=256, K=256*9. Block tile 128x256, same structure as convA.
__global__ __launch_bounds__(256, 2) void convB_kernel(
    const __bf16* __restrict__ t1pad, const __bf16* __restrict__ w2b,
    const float* __restrict__ bias2, const __bf16* __restrict__ scb,
    float* __restrict__ out) {
  __shared__ alignas(16) __bf16 lA[2][128 * 64];
  const int tid = threadIdx.x;
  const int lane = tid & 63, wv = tid >> 6;
  const int mtile = blockIdx.x;
  const int W = 36;                         // 9 taps * 256/64

  const int lrow = lane >> 3;
  const int g = ((lane & 7) ^ lrow) * 8;
  int aoffs[4];
#pragma unroll
  for (int j = 0; j < 4; ++j) {
    int m = mtile * 128 + wv * 32 + j * 8 + lrow;
    int b = m / 3136, r = m % 3136, y = r / 56, x = r % 56;
    aoffs[j] = ((b * 58 + 1 + y) * 58 + (1 + x)) * 256 + g;
  }

  const int wn = wv * 64;
  const int fr = lane & 15, kh = lane >> 4;
  const int sw = fr & 7;
  const __bf16* bbase = w2b + (wn + fr) * 256 + kh * 8;

  f32x4 acc[8][4];
#pragma unroll
  for (int f = 0; f < 8; f++)
#pragma unroll
    for (int n = 0; n < 4; n++) acc[f][n] = (f32x4){0.f, 0.f, 0.f, 0.f};

  auto decode = [&](int w, int& adelta, int& woff, int& k0) {
    int tap = w >> 2;
    k0 = (w & 3) << 6;
    int ty = (tap >= 6) ? 2 : ((tap >= 3) ? 1 : 0);
    int tx = tap - ty * 3;
    adelta = ((ty - 1) * 58 + (tx - 1)) * 256;
    woff = tap * 65536;
  };
  auto stage = [&](int adelta, int k0, int buf) {
    __bf16* dst = &lA[buf][wv * 2048];
#pragma unroll
    for (int j = 0; j < 4; ++j)
      async_load16(t1pad + (aoffs[j] + adelta + k0), dst + j * 512);
  };

  int adelta, woff, k0;
  decode(0, adelta, woff, k0);
  stage(adelta, k0, 0);
  __syncthreads();
  for (int w = 0; w < W; ++w) {
    const int buf = w & 1;
    const int cwoff = woff, ck0 = k0;
    if (w + 1 < W) {
      decode(w + 1, adelta, woff, k0);
      stage(adelta, k0, buf ^ 1);
    }
    const __bf16* bp = bbase + cwoff + ck0;
#pragma unroll
    for (int kk = 0; kk < 2; ++kk) {
      bf16x8 bfr[4], af[8];
#pragma unroll
      for (int n = 0; n < 4; ++n)
        bfr[n] = *(const bf16x8*)(bp + n * 16 * 256 + kk * 32);
#pragma unroll
      for (int f = 0; f < 8; ++f)
        af[f] = *(const bf16x8*)(&lA[buf][(f * 16 + fr) * 64 + (((kk * 4 + kh) ^ sw) * 8)]);
#pragma unroll
      for (int f = 0; f < 8; ++f)
#pragma unroll
        for (int n = 0; n < 4; ++n)
          acc[f][n] = __builtin_amdgcn_mfma_f32_16x16x32_bf16(af[f], bfr[n], acc[f][n], 0, 0, 0);
    }
    __syncthreads();
  }

  // epilogue: v = relu(acc + bias2 + sc); float4 store to NCHW d_out
  float bv[4];
#pragma unroll
  for (int n = 0; n < 4; ++n) bv[n] = bias2[wn + n * 16 + fr];
#pragma unroll
  for (int f = 0; f < 8; ++f) {
    int m0 = mtile * 128 + f * 16 + kh * 4;         // multiple of 4
    int b = m0 / 3136, r0 = m0 % 3136;              // rows don't split a float4
#pragma unroll
    for (int n = 0; n < 4; ++n) {
      int co = wn + n * 16 + fr;
      const __bf16* scp = scb + (b * 3136 + r0) * 256 + co;
      f32x4 v;
#pragma unroll
      for (int r = 0; r < 4; ++r)
        v[r] = fmaxf(acc[f][n][r] + bv[n] + (float)scp[r * 256], 0.0f);
      *(f32x4*)(out + ((b * 256 + co) * 3136 + r0)) = v;
    }
  }
}

// ---------------- launch -----------------------------------------------------
extern "C" void kernel_launch(void* const* d_in, const int* in_sizes, int n_in,
                              void* d_out, int out_size, void* d_ws, size_t ws_size,
                              hipStream_t stream) {
  const float* x   = (const float*)d_in[0];
  const float* w1  = (const float*)d_in[1];
  const float* g1  = (const float*)d_in[2];
  const float* b1  = (const float*)d_in[3];
  const float* m1  = (const float*)d_in[4];
  const float* v1  = (const float*)d_in[5];
  const float* w2  = (const float*)d_in[6];
  const float* g2  = (const float*)d_in[7];
  const float* b2  = (const float*)d_in[8];
  const float* m2  = (const float*)d_in[9];
  const float* v2  = (const float*)d_in[10];
  const float* wsc = (const float*)d_in[11];
  const float* gs  = (const float*)d_in[12];
  const float* bs  = (const float*)d_in[13];
  const float* ms  = (const float*)d_in[14];
  const float* vs  = (const float*)d_in[15];
  float* out = (float*)d_out;

  char* ws = (char*)d_ws;
  __bf16* xpad  = (__bf16*)(ws);                  // 14,745,600 B
  __bf16* t1pad = (__bf16*)(ws + 14745600);       // 27,557,888 B
  __bf16* wb    = (__bf16*)(ws + 42303488);       // 13,107,200 B
  __bf16* w2b   = (__bf16*)(ws + 55410688);       // 1,179,648 B
  __bf16* scb   = (__bf16*)(ws + 56590336);       // 25,690,112 B
  float* biasA  = (float*)(ws + 82280448);        // 2,048 B
  float* bias2  = (float*)(ws + 82282496);        // 1,024 B

  // zero xpad + t1pad (contiguous 42,303,488 B = 2,643,968 uint4)
  zero_kernel<<<dim3(10328), 256, 0, stream>>>((uint4*)ws, 2643968);
  prep_kernel<<<dim3(1891), 256, 0, stream>>>(w1, g1, b1, m1, v1, wsc, gs, bs, ms, vs,
                                              w2, g2, b2, m2, v2, wb, w2b, biasA, bias2);
  transpose_kernel<<<dim3(13, 8, 16), 256, 0, stream>>>(x, xpad);
  // 784 blocks, LPT order (q0 heaviest first via z-slowest linear dispatch)
  convA_kernel<<<dim3(98, 2, 4), 256, 0, stream>>>(xpad, wb, biasA, t1pad, scb);
  convB_kernel<<<dim3(392), 256, 0, stream>>>(t1pad, w2b, bias2, scb, out);
}

// Round 7
// 446.495 us; speedup vs baseline: 1.0328x; 1.0328x over previous
//
#include <hip/hip_runtime.h>
#include <hip/hip_bf16.h>

#define EPS 1e-5f

typedef __bf16 bf16x8 __attribute__((ext_vector_type(8)));
typedef float f32x4 __attribute__((ext_vector_type(4)));

// lds dest is WAVE-UNIFORM base; HW scatters lane i -> base + 16*i bytes
__device__ __forceinline__ void async_load16(const __bf16* g, __bf16* lds_base) {
  __builtin_amdgcn_global_load_lds(
      (const __attribute__((address_space(1))) unsigned int*)g,
      (__attribute__((address_space(3))) unsigned int*)lds_base, 16, 0, 0);
}

// ---- workspace layout (total 82,283,520 B; ws_size >= this, proven R0) -----
// xpad  : [16][30][30][512] bf16 @ 0          (14,745,600 B)
// t1pad : [16][58][58][256] bf16 @ 14,745,600 (27,557,888 B)
// wbf   : fragment-linear conv1+sc weights @ 42,303,488 (13,107,200 B)
//         [tap25][cb32][kb16][lane64][8]  (co = cb*16 + (lane&15),
//          ci = kb*32 + (lane>>4)*8 + j; cb 0-15 = w1, 16-31 = wsc)
// w2f   : fragment-linear conv2 weights @ 55,410,688 (1,179,648 B)
//         [tap9][cb16][kb8][lane64][8]
// scb   : [16][56][56][256] bf16 @ 56,590,336 (25,690,112 B)
// biasA : 512 f32                @ 82,280,448
// bias2 : 256 f32                @ 82,282,496

// A-LDS swizzle (row = 64 elems = 8 chunks of 16B):
//   LDS[row][slot] holds global k-chunk slot^(row&7); staging lane i fetches
//   global chunk (i&7)^((i>>3)&7); reader: slot = chunk ^ (fr&7). Quarter-wave
//   covers all 8 bank groups 2-way -> conflict-free (m136, verified R5: 0).

// ---------------- zero xpad + t1pad (contiguous span) -----------------------
__global__ void zero_kernel(uint4* __restrict__ p, int n4) {
  int i = blockIdx.x * 256 + threadIdx.x;
  if (i < n4) p[i] = (uint4){0u, 0u, 0u, 0u};
}

// ------- weight prep: fold BN, emit MFMA-fragment-linear bf16 layouts -------
__global__ void prep_kernel(const float* __restrict__ w1, const float* __restrict__ g1,
                            const float* __restrict__ b1, const float* __restrict__ m1,
                            const float* __restrict__ v1,
                            const float* __restrict__ wsc, const float* __restrict__ gs,
                            const float* __restrict__ bs, const float* __restrict__ ms,
                            const float* __restrict__ vs,
                            const float* __restrict__ w2, const float* __restrict__ g2,
                            const float* __restrict__ b2, const float* __restrict__ m2,
                            const float* __restrict__ v2,
                            __bf16* __restrict__ wbf, __bf16* __restrict__ w2f,
                            float* __restrict__ biasA, float* __restrict__ bias2) {
  int tid = blockIdx.x * 256 + threadIdx.x;
  if (tid < 819200) {                 // 25 taps * 32 cb * 16 kb * 64 lanes
    int lane = tid & 63;
    int rest = tid >> 6;              // < 12800
    int kb = rest & 15;
    int rest2 = rest >> 4;            // < 800
    int cb = rest2 & 31;
    int tap = rest2 >> 5;             // < 25
    int co = cb * 16 + (lane & 15);   // 0..511 (0-255 w1, 256-511 wsc)
    int ci = kb * 32 + (lane >> 4) * 8;
    bf16x8 a;
    if (co < 256) {
      float s = g1[co] * rsqrtf(v1[co] + EPS);
      const float* p = w1 + (co * 512 + ci) * 25 + tap;
#pragma unroll
      for (int j = 0; j < 8; ++j) a[j] = (__bf16)(p[j * 25] * s);
    } else {
      int c = co - 256;
      float s = gs[c] * rsqrtf(vs[c] + EPS);
      const float* p = wsc + (c * 512 + ci) * 25 + tap;
#pragma unroll
      for (int j = 0; j < 8; ++j) a[j] = (__bf16)(p[j * 25] * s);
    }
    *(bf16x8*)(wbf + (size_t)tid * 8) = a;
  } else if (tid < 892928) {          // 9 taps * 16 cb * 8 kb * 64 lanes
    int t2 = tid - 819200;
    int lane = t2 & 63;
    int rest = t2 >> 6;               // < 1152
    int kb = rest & 7;
    int rest2 = rest >> 3;            // < 144
    int cb = rest2 & 15;
    int tap = rest2 >> 4;             // < 9
    int co = cb * 16 + (lane & 15);
    int ci = kb * 32 + (lane >> 4) * 8;
    float s = g2[co] * rsqrtf(v2[co] + EPS);
    const float* p = w2 + (co * 256 + ci) * 9 + tap;
    bf16x8 a;
#pragma unroll
    for (int j = 0; j < 8; ++j) a[j] = (__bf16)(p[j * 9] * s);
    *(bf16x8*)(w2f + (size_t)t2 * 8) = a;
  } else if (tid < 893696) {
    int c = tid - 892928;
    if (c < 256)      biasA[c] = b1[c] - m1[c] * (g1[c] * rsqrtf(v1[c] + EPS));
    else if (c < 512) biasA[c] = bs[c - 256] - ms[c - 256] * (gs[c - 256] * rsqrtf(vs[c - 256] + EPS));
    else              bias2[c - 512] = b2[c - 512] - m2[c - 512] * (g2[c - 512] * rsqrtf(v2[c - 512] + EPS));
  }
}

// ------- x (NCHW f32) -> xpad (padded NHWC bf16 [16][30][30][512]) ----------
__global__ void transpose_kernel(const float* __restrict__ x, __bf16* __restrict__ xpad) {
  __shared__ __bf16 tile[64 * 65];
  const int hw0 = blockIdx.x * 64;
  const int ci0 = blockIdx.y * 64;
  const int b = blockIdx.z;
  const int tid = threadIdx.x;
#pragma unroll
  for (int it = 0; it < 16; ++it) {
    int idx = tid + 256 * it;
    int row = idx >> 6, col = idx & 63;
    int hw = hw0 + col;
    float v = (hw < 784) ? x[(b * 512 + ci0 + row) * 784 + hw] : 0.0f;
    tile[row * 65 + col] = (__bf16)v;
  }
  __syncthreads();
#pragma unroll
  for (int it = 0; it < 16; ++it) {
    int idx = tid + 256 * it;
    int orow = idx >> 6, ocol = idx & 63;
    int hw = hw0 + orow;
    if (hw < 784) {
      int h = hw / 28, w = hw % 28;
      xpad[((b * 30 + 1 + h) * 30 + 1 + w) * 512 + ci0 + ocol] = tile[ocol * 65 + orow];
    }
  }
}

// ---------------- Kernel A: conv1 + shortcut conv (parity-decomposed) -------
// Per q: GEMM M=12544, N=512, tile 128x128 (ntile 0-1 -> t1pad, 2-3 -> scb).
// Wave 64x64 (4x4 frags). A double-buffered LDS, single barrier per window;
// B direct global->VGPR from fragment-linear wbf (dense 1KB loads).
__global__ __launch_bounds__(256, 3) void convA_kernel(
    const __bf16* __restrict__ xpad, const __bf16* __restrict__ wbf,
    const float* __restrict__ biasA, __bf16* __restrict__ t1pad,
    __bf16* __restrict__ scb) {
  __shared__ alignas(16) __bf16 lA[2][128 * 64];
  const int tid = threadIdx.x;
  const int lane = tid & 63, wv = tid >> 6;
  const int mtile = blockIdx.x, ntile = blockIdx.y, q = blockIdx.z;
  const int py = q >> 1, px = q & 1;
  const int W = (py ? 2 : 3) * (px ? 2 : 3) * 8;   // taps * (512/64)

  // A staging: wave wv stages rows wv*32..+31; 4 insts of 8 rows each
  const int lrow = lane >> 3;
  const int g = ((lane & 7) ^ lrow) * 8;
  int aoffs[4];
#pragma unroll
  for (int j = 0; j < 4; ++j) {
    int m = mtile * 128 + wv * 32 + j * 8 + lrow;
    int b = m / 784, r = m % 784, hy = r / 28, hx = r % 28;
    aoffs[j] = ((b * 30 + 1 + hy) * 30 + (1 + hx)) * 512 + g;
  }

  const int wm = (wv & 1) * 64, wn = (wv >> 1) * 64;
  const int fr = lane & 15, kh = lane >> 4;
  const int sw = fr & 7;
  // B base: cb0 = ntile*8 + (wv>>1)*4 ; frag n at cb0+n, k-block kb
  const __bf16* bb = wbf + (ntile * 8 + (wv >> 1) * 4) * 8192 + lane * 8;

  f32x4 acc[4][4];
#pragma unroll
  for (int i = 0; i < 4; i++)
#pragma unroll
    for (int n = 0; n < 4; n++) acc[i][n] = (f32x4){0.f, 0.f, 0.f, 0.f};

  // window w -> (tap, k-chunk); tx fastest
  auto decode = [&](int w, int& adelta, int& btap, int& kc) {
    int tap = w >> 3;
    kc = w & 7;
    int ty, tx;
    if (px) { ty = tap >> 1; tx = tap & 1; }
    else    { ty = (tap >= 6) ? 2 : ((tap >= 3) ? 1 : 0); tx = tap - ty * 3; }
    int dy = ty - 1 + py, dx = tx - 1 + px;
    int ky = 2 * ty + py, kx = 2 * tx + px;
    adelta = (dy * 30 + dx) * 512;
    btap = (ky * 5 + kx) * 262144;
  };
  auto stage = [&](int adelta, int kc, int buf) {
    __bf16* dst = &lA[buf][wv * 2048];
#pragma unroll
    for (int j = 0; j < 4; ++j)
      async_load16(xpad + (aoffs[j] + adelta + kc * 64), dst + j * 512);
  };

  int adelta, btap, kc;
  decode(0, adelta, btap, kc);
  stage(adelta, kc, 0);
  __syncthreads();
  for (int w = 0; w < W; ++w) {
    const int buf = w & 1;
    const int cbtap = btap, ckc = kc;
    if (w + 1 < W) {                      // prefetch next A tile into other buf
      decode(w + 1, adelta, btap, kc);
      stage(adelta, kc, buf ^ 1);
    }
    const __bf16* bp = bb + cbtap + ckc * 1024;   // kb = ckc*2 (+kk) ; *512
#pragma unroll
    for (int kk = 0; kk < 2; ++kk) {
      bf16x8 bfr[4], af[4];
#pragma unroll
      for (int n = 0; n < 4; ++n)
        bfr[n] = *(const bf16x8*)(bp + n * 8192 + kk * 512);
#pragma unroll
      for (int f = 0; f < 4; ++f)
        af[f] = *(const bf16x8*)(&lA[buf][(wm + f * 16 + fr) * 64 + (((kk * 4 + kh) ^ sw) * 8)]);
#pragma unroll
      for (int f = 0; f < 4; ++f)
#pragma unroll
        for (int n = 0; n < 4; ++n)
          acc[f][n] = __builtin_amdgcn_mfma_f32_16x16x32_bf16(af[f], bfr[n], acc[f][n], 0, 0, 0);
    }
    __syncthreads();                      // also drains prefetch vmcnt, post-compute
  }

  // epilogue: C/D layout col(n)=fr, row(m)=kh*4+reg
  const bool isT1 = (ntile < 2);
  int ob[16];
#pragma unroll
  for (int f = 0; f < 4; f++)
#pragma unroll
    for (int r = 0; r < 4; r++) {
      int m = mtile * 128 + wm + f * 16 + kh * 4 + r;
      int b = m / 784, rr = m % 784, hy = rr / 28, hx = rr % 28;
      int oy = 2 * hy + py, ox = 2 * hx + px;
      ob[f * 4 + r] = isT1 ? ((b * 58 + 1 + oy) * 58 + (1 + ox)) * 256
                           : ((b * 56 + oy) * 56 + ox) * 256;
    }
  __bf16* outp = isT1 ? t1pad : scb;
#pragma unroll
  for (int n = 0; n < 4; n++) {
    int co2 = ntile * 128 + wn + n * 16 + fr;
    float bv = biasA[co2];
    int coL = isT1 ? co2 : (co2 - 256);
#pragma unroll
    for (int f = 0; f < 4; f++)
#pragma unroll
      for (int r = 0; r < 4; r++) {
        float v = acc[f][n][r] + bv;
        if (isT1) v = fmaxf(v, 0.0f);
        outp[ob[f * 4 + r] + coL] = (__bf16)v;
      }
  }
}

// ---------------- Kernel B: 3x3 conv on t1, + bias2 + scb, relu -> NCHW out -
// GEMM: M=50176, N=256, K=256*9. Tile 128x128, same structure as convA.
__global__ __launch_bounds__(256, 3) void convB_kernel(
    const __bf16* __restrict__ t1pad, const __bf16* __restrict__ w2f,
    const float* __restrict__ bias2, const __bf16* __restrict__ scb,
    float* __restrict__ out) {
  __shared__ alignas(16) __bf16 lA[2][128 * 64];
  const int tid = threadIdx.x;
  const int lane = tid & 63, wv = tid >> 6;
  const int mtile = blockIdx.x, ntile = blockIdx.y;
  const int W = 36;                         // 9 taps * (256/64)

  const int lrow = lane >> 3;
  const int g = ((lane & 7) ^ lrow) * 8;
  int aoffs[4];
#pragma unroll
  for (int j = 0; j < 4; ++j) {
    int m = mtile * 128 + wv * 32 + j * 8 + lrow;
    int b = m / 3136, r = m % 3136, y = r / 56, x = r % 56;
    aoffs[j] = ((b * 58 + 1 + y) * 58 + (1 + x)) * 256 + g;
  }

  const int wm = (wv & 1) * 64, wn = (wv >> 1) * 64;
  const int fr = lane & 15, kh = lane >> 4;
  const int sw = fr & 7;
  const __bf16* bb = w2f + (ntile * 8 + (wv >> 1) * 4) * 4096 + lane * 8;

  f32x4 acc[4][4];
#pragma unroll
  for (int i = 0; i < 4; i++)
#pragma unroll
    for (int n = 0; n < 4; n++) acc[i][n] = (f32x4){0.f, 0.f, 0.f, 0.f};

  auto decode = [&](int w, int& adelta, int& btap, int& kc) {
    int tap = w >> 2;
    kc = w & 3;
    int ty = (tap >= 6) ? 2 : ((tap >= 3) ? 1 : 0);
    int tx = tap - ty * 3;
    adelta = ((ty - 1) * 58 + (tx - 1)) * 256;
    btap = tap * 65536;
  };
  auto stage = [&](int adelta, int kc, int buf) {
    __bf16* dst = &lA[buf][wv * 2048];
#pragma unroll
    for (int j = 0; j < 4; ++j)
      async_load16(t1pad + (aoffs[j] + adelta + kc * 64), dst + j * 512);
  };

  int adelta, btap, kc;
  decode(0, adelta, btap, kc);
  stage(adelta, kc, 0);
  __syncthreads();
  for (int w = 0; w < W; ++w) {
    const int buf = w & 1;
    const int cbtap = btap, ckc = kc;
    if (w + 1 < W) {
      decode(w + 1, adelta, btap, kc);
      stage(adelta, kc, buf ^ 1);
    }
    const __bf16* bp = bb + cbtap + ckc * 1024;
#pragma unroll
    for (int kk = 0; kk < 2; ++kk) {
      bf16x8 bfr[4], af[4];
#pragma unroll
      for (int n = 0; n < 4; ++n)
        bfr[n] = *(const bf16x8*)(bp + n * 4096 + kk * 512);
#pragma unroll
      for (int f = 0; f < 4; ++f)
        af[f] = *(const bf16x8*)(&lA[buf][(wm + f * 16 + fr) * 64 + (((kk * 4 + kh) ^ sw) * 8)]);
#pragma unroll
      for (int f = 0; f < 4; ++f)
#pragma unroll
        for (int n = 0; n < 4; ++n)
          acc[f][n] = __builtin_amdgcn_mfma_f32_16x16x32_bf16(af[f], bfr[n], acc[f][n], 0, 0, 0);
    }
    __syncthreads();
  }

  // epilogue: v = relu(acc + bias2 + sc); float4 store to NCHW d_out
  float bv[4];
#pragma unroll
  for (int n = 0; n < 4; ++n) bv[n] = bias2[ntile * 128 + wn + n * 16 + fr];
#pragma unroll
  for (int f = 0; f < 4; ++f) {
    int m0 = mtile * 128 + wm + f * 16 + kh * 4;    // multiple of 4
    int b = m0 / 3136, r0 = m0 % 3136;              // rows don't split a float4
#pragma unroll
    for (int n = 0; n < 4; ++n) {
      int co = ntile * 128 + wn + n * 16 + fr;
      const __bf16* scp = scb + (b * 3136 + r0) * 256 + co;
      f32x4 v;
#pragma unroll
      for (int r = 0; r < 4; ++r)
        v[r] = fmaxf(acc[f][n][r] + bv[n] + (float)scp[r * 256], 0.0f);
      *(f32x4*)(out + ((b * 256 + co) * 3136 + r0)) = v;
    }
  }
}

// ---------------- launch -----------------------------------------------------
extern "C" void kernel_launch(void* const* d_in, const int* in_sizes, int n_in,
                              void* d_out, int out_size, void* d_ws, size_t ws_size,
                              hipStream_t stream) {
  const float* x   = (const float*)d_in[0];
  const float* w1  = (const float*)d_in[1];
  const float* g1  = (const float*)d_in[2];
  const float* b1  = (const float*)d_in[3];
  const float* m1  = (const float*)d_in[4];
  const float* v1  = (const float*)d_in[5];
  const float* w2  = (const float*)d_in[6];
  const float* g2  = (const float*)d_in[7];
  const float* b2  = (const float*)d_in[8];
  const float* m2  = (const float*)d_in[9];
  const float* v2  = (const float*)d_in[10];
  const float* wsc = (const float*)d_in[11];
  const float* gs  = (const float*)d_in[12];
  const float* bs  = (const float*)d_in[13];
  const float* ms  = (const float*)d_in[14];
  const float* vs  = (const float*)d_in[15];
  float* out = (float*)d_out;

  char* ws = (char*)d_ws;
  __bf16* xpad  = (__bf16*)(ws);                  // 14,745,600 B
  __bf16* t1pad = (__bf16*)(ws + 14745600);       // 27,557,888 B
  __bf16* wbf   = (__bf16*)(ws + 42303488);       // 13,107,200 B
  __bf16* w2f   = (__bf16*)(ws + 55410688);       // 1,179,648 B
  __bf16* scb   = (__bf16*)(ws + 56590336);       // 25,690,112 B
  float* biasA  = (float*)(ws + 82280448);        // 2,048 B
  float* bias2  = (float*)(ws + 82282496);        // 1,024 B

  // zero xpad + t1pad (contiguous 42,303,488 B = 2,643,968 uint4)
  zero_kernel<<<dim3(10328), 256, 0, stream>>>((uint4*)ws, 2643968);
  prep_kernel<<<dim3(3491), 256, 0, stream>>>(w1, g1, b1, m1, v1, wsc, gs, bs, ms, vs,
                                              w2, g2, b2, m2, v2, wbf, w2f, biasA, bias2);
  transpose_kernel<<<dim3(13, 8, 16), 256, 0, stream>>>(x, xpad);
  // 1568 blocks (~3/CU resident, heavy q0 dispatched first)
  convA_kernel<<<dim3(98, 4, 4), 256, 0, stream>>>(xpad, wbf, biasA, t1pad, scb);
  // 784 blocks
  convB_kernel<<<dim3(392, 2), 256, 0, stream>>>(t1pad, w2f, bias2, scb, out);
}

// Round 8
// 425.129 us; speedup vs baseline: 1.0847x; 1.0503x over previous
//
#include <hip/hip_runtime.h>
#include <hip/hip_bf16.h>

#define EPS 1e-5f

typedef __bf16 bf16x8 __attribute__((ext_vector_type(8)));
typedef float f32x4 __attribute__((ext_vector_type(4)));

// lds dest is WAVE-UNIFORM base; HW scatters lane i -> base + 16*i bytes
__device__ __forceinline__ void async_load16(const __bf16* g, __bf16* lds_base) {
  __builtin_amdgcn_global_load_lds(
      (const __attribute__((address_space(1))) unsigned int*)g,
      (__attribute__((address_space(3))) unsigned int*)lds_base, 16, 0, 0);
}

// ---- workspace layout (total 82,283,520 B; ws_size >= this, proven R0) -----
// xpad  : [16][30][30][512] bf16 @ 0          (14,745,600 B)
// t1pad : [16][58][58][256] bf16 @ 14,745,600 (27,557,888 B)
// wbf   : fragment-linear conv1+sc weights @ 42,303,488 (13,107,200 B)
//         [tap25][cb32][kb16][lane64][8]  (co = cb*16 + (lane&15),
//          ci = kb*32 + (lane>>4)*8 + j; cb 0-15 = w1, 16-31 = wsc)
// w2f   : fragment-linear conv2 weights @ 55,410,688 (1,179,648 B)
//         [tap9][cb16][kb8][lane64][8]
// scb   : [16][56][56][256] bf16 @ 56,590,336 (25,690,112 B)
// biasA : 512 f32                @ 82,280,448
// bias2 : 256 f32                @ 82,282,496

// A-LDS swizzle (row = 64 elems = 8 chunks of 16B):
//   LDS[row][slot] holds global k-chunk slot^(row&7); staging lane i fetches
//   global chunk (i&7)^((i>>3)&7); reader: slot = chunk ^ (fr&7). Conflict-free
//   (verified R5: SQ_LDS_BANK_CONFLICT = 0).

// XCD swizzle model: linear workgroup id round-robins XCDs (id % 8). Blocks
// sharing an A-tile are placed 8 ids apart -> same XCD -> A fetched into one
// L2 instead of ntile-many.

// ---------------- zero xpad + t1pad (contiguous span) -----------------------
__global__ void zero_kernel(uint4* __restrict__ p, int n4) {
  int i = blockIdx.x * 256 + threadIdx.x;
  if (i < n4) p[i] = (uint4){0u, 0u, 0u, 0u};
}

// ------- weight prep: coalesced LDS-staged fold+relayout --------------------
// blocks 0-511: wbf (cb = bx>>4, kb = bx&15); 512-639: w2f; 640-642: biases.
__global__ void prep_kernel(const float* __restrict__ w1, const float* __restrict__ g1,
                            const float* __restrict__ b1, const float* __restrict__ m1,
                            const float* __restrict__ v1,
                            const float* __restrict__ wsc, const float* __restrict__ gs,
                            const float* __restrict__ bs, const float* __restrict__ ms,
                            const float* __restrict__ vs,
                            const float* __restrict__ w2, const float* __restrict__ g2,
                            const float* __restrict__ b2, const float* __restrict__ m2,
                            const float* __restrict__ v2,
                            __bf16* __restrict__ wbf, __bf16* __restrict__ w2f,
                            float* __restrict__ biasA, float* __restrict__ bias2) {
  __shared__ float lt[12800];
  __shared__ float sc[16];
  const int bx = blockIdx.x, tid = threadIdx.x;
  if (bx < 512) {
    const int cb = bx >> 4, kb = bx & 15;
    const bool isW1 = cb < 16;
    const int co0 = (isW1 ? cb : cb - 16) * 16;
    const float* src = isW1 ? w1 : wsc;
    if (tid < 16) {
      float gv = isW1 ? g1[co0 + tid] : gs[co0 + tid];
      float vv = isW1 ? v1[co0 + tid] : vs[co0 + tid];
      sc[tid] = gv * rsqrtf(vv + EPS);
    }
    const size_t base = ((size_t)co0 * 512 + kb * 32) * 25;
    for (int it = 0; it < 50; ++it) {           // 12800 floats, coalesced
      int idx = tid + it * 256;
      int col = idx / 800, rem = idx - col * 800;   // rem = cil*25 + tap
      lt[idx] = src[base + (size_t)col * 12800 + rem];
    }
    __syncthreads();
    for (int it = 0; it < 50; ++it) {           // 12800 bf16 out, coalesced 1KB
      int o = tid + it * 256;
      int tap = o >> 9, r = o & 511;
      int lane = r >> 3, j = r & 7;
      int col = lane & 15, cil = ((lane >> 4) << 3) + j;
      float v = lt[col * 800 + cil * 25 + tap] * sc[col];
      wbf[(size_t)tap * 262144 + ((size_t)cb * 16 + kb) * 512 + r] = (__bf16)v;
    }
  } else if (bx < 640) {
    const int b2x = bx - 512;
    const int cb = b2x >> 3, kb = b2x & 7;
    const int co0 = cb * 16;
    if (tid < 16) sc[tid] = g2[co0 + tid] * rsqrtf(v2[co0 + tid] + EPS);
    const size_t base = ((size_t)co0 * 256 + kb * 32) * 9;
    for (int it = 0; it < 18; ++it) {           // 4608 floats
      int idx = tid + it * 256;
      int col = idx / 288, rem = idx - col * 288;   // rem = cil*9 + tap
      lt[idx] = w2[base + (size_t)col * 2304 + rem];
    }
    __syncthreads();
    for (int it = 0; it < 18; ++it) {
      int o = tid + it * 256;
      int tap = o >> 9, r = o & 511;
      int lane = r >> 3, j = r & 7;
      int col = lane & 15, cil = ((lane >> 4) << 3) + j;
      float v = lt[col * 288 + cil * 9 + tap] * sc[col];
      w2f[(size_t)tap * 65536 + ((size_t)cb * 8 + kb) * 512 + r] = (__bf16)v;
    }
  } else {
    int c = (bx - 640) * 256 + tid;             // 0..767
    if (c < 256)      biasA[c] = b1[c] - m1[c] * (g1[c] * rsqrtf(v1[c] + EPS));
    else if (c < 512) biasA[c] = bs[c - 256] - ms[c - 256] * (gs[c - 256] * rsqrtf(vs[c - 256] + EPS));
    else              bias2[c - 512] = b2[c - 512] - m2[c - 512] * (g2[c - 512] * rsqrtf(v2[c - 512] + EPS));
  }
}

// ------- x (NCHW f32) -> xpad (padded NHWC bf16 [16][30][30][512]) ----------
__global__ void transpose_kernel(const float* __restrict__ x, __bf16* __restrict__ xpad) {
  __shared__ __bf16 tile[64 * 65];
  const int hw0 = blockIdx.x * 64;
  const int ci0 = blockIdx.y * 64;
  const int b = blockIdx.z;
  const int tid = threadIdx.x;
#pragma unroll
  for (int it = 0; it < 16; ++it) {
    int idx = tid + 256 * it;
    int row = idx >> 6, col = idx & 63;
    int hw = hw0 + col;
    float v = (hw < 784) ? x[(b * 512 + ci0 + row) * 784 + hw] : 0.0f;
    tile[row * 65 + col] = (__bf16)v;
  }
  __syncthreads();
#pragma unroll
  for (int it = 0; it < 16; ++it) {
    int idx = tid + 256 * it;
    int orow = idx >> 6, ocol = idx & 63;
    int hw = hw0 + orow;
    if (hw < 784) {
      int h = hw / 28, w = hw % 28;
      xpad[((b * 30 + 1 + h) * 30 + 1 + w) * 512 + ci0 + ocol] = tile[ocol * 65 + orow];
    }
  }
}

// ---------------- Kernel A: conv1 + shortcut conv (parity-decomposed) -------
// 1D grid 1568; decode keeps A-sharing blocks (same mtile,q) 8 ids apart.
__global__ __launch_bounds__(256, 3) void convA_kernel(
    const __bf16* __restrict__ xpad, const __bf16* __restrict__ wbf,
    const float* __restrict__ biasA, __bf16* __restrict__ t1pad,
    __bf16* __restrict__ scb) {
  __shared__ alignas(16) __bf16 lA[2][128 * 64];
  const int tid = threadIdx.x;
  const int lane = tid & 63, wv = tid >> 6;
  const int u = blockIdx.x;
  const int mq = (u >> 5) * 8 + (u & 7);      // 0..391
  const int ntile = (u >> 3) & 3;
  const int mtile = mq % 98;
  const int q = mq / 98;
  const int py = q >> 1, px = q & 1;
  const int W = (py ? 2 : 3) * (px ? 2 : 3) * 8;   // taps * (512/64)

  // A staging: wave wv stages rows wv*32..+31; 4 insts of 8 rows each
  const int lrow = lane >> 3;
  const int g = ((lane & 7) ^ lrow) * 8;
  int aoffs[4];
#pragma unroll
  for (int j = 0; j < 4; ++j) {
    int m = mtile * 128 + wv * 32 + j * 8 + lrow;
    int b = m / 784, r = m % 784, hy = r / 28, hx = r % 28;
    aoffs[j] = ((b * 30 + 1 + hy) * 30 + (1 + hx)) * 512 + g;
  }

  const int wm = (wv & 1) * 64, wn = (wv >> 1) * 64;
  const int fr = lane & 15, kh = lane >> 4;
  const int sw = fr & 7;
  const __bf16* bb = wbf + (ntile * 8 + (wv >> 1) * 4) * 8192 + lane * 8;

  f32x4 acc[4][4];
#pragma unroll
  for (int i = 0; i < 4; i++)
#pragma unroll
    for (int n = 0; n < 4; n++) acc[i][n] = (f32x4){0.f, 0.f, 0.f, 0.f};

  auto decode = [&](int w, int& adelta, int& btap, int& kc) {
    int tap = w >> 3;
    kc = w & 7;
    int ty, tx;
    if (px) { ty = tap >> 1; tx = tap & 1; }
    else    { ty = (tap >= 6) ? 2 : ((tap >= 3) ? 1 : 0); tx = tap - ty * 3; }
    int dy = ty - 1 + py, dx = tx - 1 + px;
    int ky = 2 * ty + py, kx = 2 * tx + px;
    adelta = (dy * 30 + dx) * 512;
    btap = (ky * 5 + kx) * 262144;
  };
  auto stage = [&](int adelta, int kc, int buf) {
    __bf16* dst = &lA[buf][wv * 2048];
#pragma unroll
    for (int j = 0; j < 4; ++j)
      async_load16(xpad + (aoffs[j] + adelta + kc * 64), dst + j * 512);
  };

  int adelta, btap, kc;
  decode(0, adelta, btap, kc);
  stage(adelta, kc, 0);
  __syncthreads();
  for (int w = 0; w < W; ++w) {
    const int buf = w & 1;
    const int cbtap = btap, ckc = kc;
    if (w + 1 < W) {                      // prefetch next A tile into other buf
      decode(w + 1, adelta, btap, kc);
      stage(adelta, kc, buf ^ 1);
    }
    const __bf16* bp = bb + cbtap + ckc * 1024;
#pragma unroll
    for (int kk = 0; kk < 2; ++kk) {
      bf16x8 bfr[4], af[4];
#pragma unroll
      for (int n = 0; n < 4; ++n)
        bfr[n] = *(const bf16x8*)(bp + n * 8192 + kk * 512);
#pragma unroll
      for (int f = 0; f < 4; ++f)
        af[f] = *(const bf16x8*)(&lA[buf][(wm + f * 16 + fr) * 64 + (((kk * 4 + kh) ^ sw) * 8)]);
#pragma unroll
      for (int f = 0; f < 4; ++f)
#pragma unroll
        for (int n = 0; n < 4; ++n)
          acc[f][n] = __builtin_amdgcn_mfma_f32_16x16x32_bf16(af[f], bfr[n], acc[f][n], 0, 0, 0);
    }
    __syncthreads();
  }

  // epilogue: C/D layout col(n)=fr, row(m)=kh*4+reg
  const bool isT1 = (ntile < 2);
  int ob[16];
#pragma unroll
  for (int f = 0; f < 4; f++)
#pragma unroll
    for (int r = 0; r < 4; r++) {
      int m = mtile * 128 + wm + f * 16 + kh * 4 + r;
      int b = m / 784, rr = m % 784, hy = rr / 28, hx = rr % 28;
      int oy = 2 * hy + py, ox = 2 * hx + px;
      ob[f * 4 + r] = isT1 ? ((b * 58 + 1 + oy) * 58 + (1 + ox)) * 256
                           : ((b * 56 + oy) * 56 + ox) * 256;
    }
  __bf16* outp = isT1 ? t1pad : scb;
#pragma unroll
  for (int n = 0; n < 4; n++) {
    int co2 = ntile * 128 + wn + n * 16 + fr;
    float bv = biasA[co2];
    int coL = isT1 ? co2 : (co2 - 256);
#pragma unroll
    for (int f = 0; f < 4; f++)
#pragma unroll
      for (int r = 0; r < 4; r++) {
        float v = acc[f][n][r] + bv;
        if (isT1) v = fmaxf(v, 0.0f);
        outp[ob[f * 4 + r] + coL] = (__bf16)v;
      }
  }
}

// ---------------- Kernel B: 3x3 conv on t1, + bias2 + scb, relu -> NCHW out -
// 1D grid 784; A-sharing pair (ntile 0/1) placed 8 ids apart (same XCD).
__global__ __launch_bounds__(256, 3) void convB_kernel(
    const __bf16* __restrict__ t1pad, const __bf16* __restrict__ w2f,
    const float* __restrict__ bias2, const __bf16* __restrict__ scb,
    float* __restrict__ out) {
  __shared__ alignas(16) __bf16 lA[2][128 * 64];
  const int tid = threadIdx.x;
  const int lane = tid & 63, wv = tid >> 6;
  const int u = blockIdx.x;
  const int mtile = (u >> 4) * 8 + (u & 7);   // 0..391
  const int ntile = (u >> 3) & 1;
  const int W = 36;                           // 9 taps * (256/64)

  const int lrow = lane >> 3;
  const int g = ((lane & 7) ^ lrow) * 8;
  int aoffs[4];
#pragma unroll
  for (int j = 0; j < 4; ++j) {
    int m = mtile * 128 + wv * 32 + j * 8 + lrow;
    int b = m / 3136, r = m % 3136, y = r / 56, x = r % 56;
    aoffs[j] = ((b * 58 + 1 + y) * 58 + (1 + x)) * 256 + g;
  }

  const int wm = (wv & 1) * 64, wn = (wv >> 1) * 64;
  const int fr = lane & 15, kh = lane >> 4;
  const int sw = fr & 7;
  const __bf16* bb = w2f + (ntile * 8 + (wv >> 1) * 4) * 4096 + lane * 8;

  f32x4 acc[4][4];
#pragma unroll
  for (int i = 0; i < 4; i++)
#pragma unroll
    for (int n = 0; n < 4; n++) acc[i][n] = (f32x4){0.f, 0.f, 0.f, 0.f};

  auto decode = [&](int w, int& adelta, int& btap, int& kc) {
    int tap = w >> 2;
    kc = w & 3;
    int ty = (tap >= 6) ? 2 : ((tap >= 3) ? 1 : 0);
    int tx = tap - ty * 3;
    adelta = ((ty - 1) * 58 + (tx - 1)) * 256;
    btap = tap * 65536;
  };
  auto stage = [&](int adelta, int kc, int buf) {
    __bf16* dst = &lA[buf][wv * 2048];
#pragma unroll
    for (int j = 0; j < 4; ++j)
      async_load16(t1pad + (aoffs[j] + adelta + kc * 64), dst + j * 512);
  };

  int adelta, btap, kc;
  decode(0, adelta, btap, kc);
  stage(adelta, kc, 0);
  __syncthreads();
  for (int w = 0; w < W; ++w) {
    const int buf = w & 1;
    const int cbtap = btap, ckc = kc;
    if (w + 1 < W) {
      decode(w + 1, adelta, btap, kc);
      stage(adelta, kc, buf ^ 1);
    }
    const __bf16* bp = bb + cbtap + ckc * 1024;
#pragma unroll
    for (int kk = 0; kk < 2; ++kk) {
      bf16x8 bfr[4], af[4];
#pragma unroll
      for (int n = 0; n < 4; ++n)
        bfr[n] = *(const bf16x8*)(bp + n * 4096 + kk * 512);
#pragma unroll
      for (int f = 0; f < 4; ++f)
        af[f] = *(const bf16x8*)(&lA[buf][(wm + f * 16 + fr) * 64 + (((kk * 4 + kh) ^ sw) * 8)]);
#pragma unroll
      for (int f = 0; f < 4; ++f)
#pragma unroll
        for (int n = 0; n < 4; ++n)
          acc[f][n] = __builtin_amdgcn_mfma_f32_16x16x32_bf16(af[f], bfr[n], acc[f][n], 0, 0, 0);
    }
    __syncthreads();
  }

  // epilogue: v = relu(acc + bias2 + sc); float4 store to NCHW d_out
  float bv[4];
#pragma unroll
  for (int n = 0; n < 4; ++n) bv[n] = bias2[ntile * 128 + wn + n * 16 + fr];
#pragma unroll
  for (int f = 0; f < 4; ++f) {
    int m0 = mtile * 128 + wm + f * 16 + kh * 4;    // multiple of 4
    int b = m0 / 3136, r0 = m0 % 3136;              // rows don't split a float4
#pragma unroll
    for (int n = 0; n < 4; ++n) {
      int co = ntile * 128 + wn + n * 16 + fr;
      const __bf16* scp = scb + (b * 3136 + r0) * 256 + co;
      f32x4 v;
#pragma unroll
      for (int r = 0; r < 4; ++r)
        v[r] = fmaxf(acc[f][n][r] + bv[n] + (float)scp[r * 256], 0.0f);
      *(f32x4*)(out + ((b * 256 + co) * 3136 + r0)) = v;
    }
  }
}

// ---------------- launch -----------------------------------------------------
extern "C" void kernel_launch(void* const* d_in, const int* in_sizes, int n_in,
                              void* d_out, int out_size, void* d_ws, size_t ws_size,
                              hipStream_t stream) {
  const float* x   = (const float*)d_in[0];
  const float* w1  = (const float*)d_in[1];
  const float* g1  = (const float*)d_in[2];
  const float* b1  = (const float*)d_in[3];
  const float* m1  = (const float*)d_in[4];
  const float* v1  = (const float*)d_in[5];
  const float* w2  = (const float*)d_in[6];
  const float* g2  = (const float*)d_in[7];
  const float* b2  = (const float*)d_in[8];
  const float* m2  = (const float*)d_in[9];
  const float* v2  = (const float*)d_in[10];
  const float* wsc = (const float*)d_in[11];
  const float* gs  = (const float*)d_in[12];
  const float* bs  = (const float*)d_in[13];
  const float* ms  = (const float*)d_in[14];
  const float* vs  = (const float*)d_in[15];
  float* out = (float*)d_out;

  char* ws = (char*)d_ws;
  __bf16* xpad  = (__bf16*)(ws);                  // 14,745,600 B
  __bf16* t1pad = (__bf16*)(ws + 14745600);       // 27,557,888 B
  __bf16* wbf   = (__bf16*)(ws + 42303488);       // 13,107,200 B
  __bf16* w2f   = (__bf16*)(ws + 55410688);       // 1,179,648 B
  __bf16* scb   = (__bf16*)(ws + 56590336);       // 25,690,112 B
  float* biasA  = (float*)(ws + 82280448);        // 2,048 B
  float* bias2  = (float*)(ws + 82282496);        // 1,024 B

  // zero xpad + t1pad (contiguous 42,303,488 B = 2,643,968 uint4)
  zero_kernel<<<dim3(10328), 256, 0, stream>>>((uint4*)ws, 2643968);
  prep_kernel<<<dim3(643), 256, 0, stream>>>(w1, g1, b1, m1, v1, wsc, gs, bs, ms, vs,
                                             w2, g2, b2, m2, v2, wbf, w2f, biasA, bias2);
  transpose_kernel<<<dim3(13, 8, 16), 256, 0, stream>>>(x, xpad);
  convA_kernel<<<dim3(1568), 256, 0, stream>>>(xpad, wbf, biasA, t1pad, scb);
  convB_kernel<<<dim3(784), 256, 0, stream>>>(t1pad, w2f, bias2, scb, out);
}

// Round 9
// 417.824 us; speedup vs baseline: 1.1036x; 1.0175x over previous
//
#include <hip/hip_runtime.h>
#include <hip/hip_bf16.h>

#define EPS 1e-5f

typedef __bf16 bf16x8 __attribute__((ext_vector_type(8)));
typedef float f32x4 __attribute__((ext_vector_type(4)));

// lds dest is WAVE-UNIFORM base; HW scatters lane i -> base + 16*i bytes
__device__ __forceinline__ void async_load16(const __bf16* g, __bf16* lds_base) {
  __builtin_amdgcn_global_load_lds(
      (const __attribute__((address_space(1))) unsigned int*)g,
      (__attribute__((address_space(3))) unsigned int*)lds_base, 16, 0, 0);
}

// ---- workspace layout (total 82,283,520 B; ws_size >= this, proven R0) -----
// xpad  : [16][30][30][512] bf16 @ 0          (14,745,600 B)
// t1pad : [16][58][58][256] bf16 @ 14,745,600 (27,557,888 B)
// wbf   : fragment-linear conv1+sc weights @ 42,303,488 (13,107,200 B)
//         [tap25][cb32][kb16][lane64][8]
// w2f   : fragment-linear conv2 weights @ 55,410,688 (1,179,648 B)
//         [tap9][cb16][kb8][lane64][8]
// scb   : [16][56][56][256] bf16 @ 56,590,336 (25,690,112 B)
// biasA : 512 f32                @ 82,280,448
// bias2 : 256 f32                @ 82,282,496

// A-LDS swizzle: LDS[row][slot] = global chunk slot^(row&7); conflict-free
// (verified R5: SQ_LDS_BANK_CONFLICT = 0).
// XCD swizzle: A-sharing blocks 8 linear-ids apart (verified R8: FETCH -57%).

// ---------------- zero xpad + t1pad (contiguous span) -----------------------
__global__ void zero_kernel(uint4* __restrict__ p, int n4) {
  int i = blockIdx.x * 256 + threadIdx.x;
  if (i < n4) p[i] = (uint4){0u, 0u, 0u, 0u};
}

// ------- weight prep: coalesced LDS-staged fold+relayout --------------------
__global__ void prep_kernel(const float* __restrict__ w1, const float* __restrict__ g1,
                            const float* __restrict__ b1, const float* __restrict__ m1,
                            const float* __restrict__ v1,
                            const float* __restrict__ wsc, const float* __restrict__ gs,
                            const float* __restrict__ bs, const float* __restrict__ ms,
                            const float* __restrict__ vs,
                            const float* __restrict__ w2, const float* __restrict__ g2,
                            const float* __restrict__ b2, const float* __restrict__ m2,
                            const float* __restrict__ v2,
                            __bf16* __restrict__ wbf, __bf16* __restrict__ w2f,
                            float* __restrict__ biasA, float* __restrict__ bias2) {
  __shared__ float lt[12800];
  __shared__ float sc[16];
  const int bx = blockIdx.x, tid = threadIdx.x;
  if (bx < 512) {
    const int cb = bx >> 4, kb = bx & 15;
    const bool isW1 = cb < 16;
    const int co0 = (isW1 ? cb : cb - 16) * 16;
    const float* src = isW1 ? w1 : wsc;
    if (tid < 16) {
      float gv = isW1 ? g1[co0 + tid] : gs[co0 + tid];
      float vv = isW1 ? v1[co0 + tid] : vs[co0 + tid];
      sc[tid] = gv * rsqrtf(vv + EPS);
    }
    const size_t base = ((size_t)co0 * 512 + kb * 32) * 25;
    for (int it = 0; it < 50; ++it) {
      int idx = tid + it * 256;
      int col = idx / 800, rem = idx - col * 800;
      lt[idx] = src[base + (size_t)col * 12800 + rem];
    }
    __syncthreads();
    for (int it = 0; it < 50; ++it) {
      int o = tid + it * 256;
      int tap = o >> 9, r = o & 511;
      int lane = r >> 3, j = r & 7;
      int col = lane & 15, cil = ((lane >> 4) << 3) + j;
      float v = lt[col * 800 + cil * 25 + tap] * sc[col];
      wbf[(size_t)tap * 262144 + ((size_t)cb * 16 + kb) * 512 + r] = (__bf16)v;
    }
  } else if (bx < 640) {
    const int b2x = bx - 512;
    const int cb = b2x >> 3, kb = b2x & 7;
    const int co0 = cb * 16;
    if (tid < 16) sc[tid] = g2[co0 + tid] * rsqrtf(v2[co0 + tid] + EPS);
    const size_t base = ((size_t)co0 * 256 + kb * 32) * 9;
    for (int it = 0; it < 18; ++it) {
      int idx = tid + it * 256;
      int col = idx / 288, rem = idx - col * 288;
      lt[idx] = w2[base + (size_t)col * 2304 + rem];
    }
    __syncthreads();
    for (int it = 0; it < 18; ++it) {
      int o = tid + it * 256;
      int tap = o >> 9, r = o & 511;
      int lane = r >> 3, j = r & 7;
      int col = lane & 15, cil = ((lane >> 4) << 3) + j;
      float v = lt[col * 288 + cil * 9 + tap] * sc[col];
      w2f[(size_t)tap * 65536 + ((size_t)cb * 8 + kb) * 512 + r] = (__bf16)v;
    }
  } else {
    int c = (bx - 640) * 256 + tid;
    if (c < 256)      biasA[c] = b1[c] - m1[c] * (g1[c] * rsqrtf(v1[c] + EPS));
    else if (c < 512) biasA[c] = bs[c - 256] - ms[c - 256] * (gs[c - 256] * rsqrtf(vs[c - 256] + EPS));
    else              bias2[c - 512] = b2[c - 512] - m2[c - 512] * (g2[c - 512] * rsqrtf(v2[c - 512] + EPS));
  }
}

// ------- x (NCHW f32) -> xpad (padded NHWC bf16 [16][30][30][512]) ----------
__global__ void transpose_kernel(const float* __restrict__ x, __bf16* __restrict__ xpad) {
  __shared__ __bf16 tile[64 * 65];
  const int hw0 = blockIdx.x * 64;
  const int ci0 = blockIdx.y * 64;
  const int b = blockIdx.z;
  const int tid = threadIdx.x;
#pragma unroll
  for (int it = 0; it < 16; ++it) {
    int idx = tid + 256 * it;
    int row = idx >> 6, col = idx & 63;
    int hw = hw0 + col;
    float v = (hw < 784) ? x[(b * 512 + ci0 + row) * 784 + hw] : 0.0f;
    tile[row * 65 + col] = (__bf16)v;
  }
  __syncthreads();
#pragma unroll
  for (int it = 0; it < 16; ++it) {
    int idx = tid + 256 * it;
    int orow = idx >> 6, ocol = idx & 63;
    int hw = hw0 + orow;
    if (hw < 784) {
      int h = hw / 28, w = hw % 28;
      xpad[((b * 30 + 1 + h) * 30 + 1 + w) * 512 + ci0 + ocol] = tile[ocol * 65 + orow];
    }
  }
}

// ---------------- Kernel A: conv1 + shortcut conv (parity-decomposed) -------
// 1D grid 1568; A-sharing blocks 8 ids apart. B software-pipelined in regs
// (double-buffer b0/b1, loop unrolled x2; W always even).
__global__ __launch_bounds__(256, 3) void convA_kernel(
    const __bf16* __restrict__ xpad, const __bf16* __restrict__ wbf,
    const float* __restrict__ biasA, __bf16* __restrict__ t1pad,
    __bf16* __restrict__ scb) {
  __shared__ alignas(16) __bf16 lA[2][128 * 64];
  const int tid = threadIdx.x;
  const int lane = tid & 63, wv = tid >> 6;
  const int u = blockIdx.x;
  const int mq = (u >> 5) * 8 + (u & 7);      // 0..391
  const int ntile = (u >> 3) & 3;
  const int mtile = mq % 98;
  const int q = mq / 98;
  const int py = q >> 1, px = q & 1;
  const int W = (py ? 2 : 3) * (px ? 2 : 3) * 8;

  const int lrow = lane >> 3;
  const int g = ((lane & 7) ^ lrow) * 8;
  int aoffs[4];
#pragma unroll
  for (int j = 0; j < 4; ++j) {
    int m = mtile * 128 + wv * 32 + j * 8 + lrow;
    int b = m / 784, r = m % 784, hy = r / 28, hx = r % 28;
    aoffs[j] = ((b * 30 + 1 + hy) * 30 + (1 + hx)) * 512 + g;
  }

  const int wm = (wv & 1) * 64, wn = (wv >> 1) * 64;
  const int fr = lane & 15, kh = lane >> 4;
  const int sw = fr & 7;
  const __bf16* bb = wbf + (ntile * 8 + (wv >> 1) * 4) * 8192 + lane * 8;

  f32x4 acc[4][4];
#pragma unroll
  for (int i = 0; i < 4; i++)
#pragma unroll
    for (int n = 0; n < 4; n++) acc[i][n] = (f32x4){0.f, 0.f, 0.f, 0.f};

  auto decode = [&](int w, int& adelta, int& btap, int& kc) {
    int tap = w >> 3;
    kc = w & 7;
    int ty, tx;
    if (px) { ty = tap >> 1; tx = tap & 1; }
    else    { ty = (tap >= 6) ? 2 : ((tap >= 3) ? 1 : 0); tx = tap - ty * 3; }
    int dy = ty - 1 + py, dx = tx - 1 + px;
    int ky = 2 * ty + py, kx = 2 * tx + px;
    adelta = (dy * 30 + dx) * 512;
    btap = (ky * 5 + kx) * 262144;
  };
  auto stage = [&](int adelta, int kc, int buf) {
    __bf16* dst = &lA[buf][wv * 2048];
#pragma unroll
    for (int j = 0; j < 4; ++j)
      async_load16(xpad + (aoffs[j] + adelta + kc * 64), dst + j * 512);
  };
  auto loadB = [&](int btap, int kc, bf16x8* d) {
    const __bf16* bp = bb + btap + kc * 1024;
#pragma unroll
    for (int n = 0; n < 4; ++n) {
      d[n]     = *(const bf16x8*)(bp + n * 8192);
      d[4 + n] = *(const bf16x8*)(bp + n * 8192 + 512);
    }
  };
  auto compute = [&](const __bf16* lds, const bf16x8* bc) {
#pragma unroll
    for (int kk = 0; kk < 2; ++kk) {
      bf16x8 af[4];
#pragma unroll
      for (int f = 0; f < 4; ++f)
        af[f] = *(const bf16x8*)(lds + (wm + f * 16 + fr) * 64 + (((kk * 4 + kh) ^ sw) * 8));
#pragma unroll
      for (int f = 0; f < 4; ++f)
#pragma unroll
        for (int n = 0; n < 4; ++n)
          acc[f][n] = __builtin_amdgcn_mfma_f32_16x16x32_bf16(af[f], bc[kk * 4 + n], acc[f][n], 0, 0, 0);
    }
  };

  bf16x8 b0[8], b1[8];
  int adelta, btap, kc;
  decode(0, adelta, btap, kc);
  stage(adelta, kc, 0);
  loadB(btap, kc, b0);
  __syncthreads();
  for (int w = 0; w < W; w += 2) {
    decode(w + 1, adelta, btap, kc);        // w+1 <= W-1 (W even)
    stage(adelta, kc, 1);
    loadB(btap, kc, b1);
    compute(lA[0], b0);
    __syncthreads();
    if (w + 2 < W) {
      decode(w + 2, adelta, btap, kc);
      stage(adelta, kc, 0);
      loadB(btap, kc, b0);
    }
    compute(lA[1], b1);
    __syncthreads();
  }

  // epilogue: C/D layout col(n)=fr, row(m)=kh*4+reg
  const bool isT1 = (ntile < 2);
  int ob[16];
#pragma unroll
  for (int f = 0; f < 4; f++)
#pragma unroll
    for (int r = 0; r < 4; r++) {
      int m = mtile * 128 + wm + f * 16 + kh * 4 + r;
      int b = m / 784, rr = m % 784, hy = rr / 28, hx = rr % 28;
      int oy = 2 * hy + py, ox = 2 * hx + px;
      ob[f * 4 + r] = isT1 ? ((b * 58 + 1 + oy) * 58 + (1 + ox)) * 256
                           : ((b * 56 + oy) * 56 + ox) * 256;
    }
  __bf16* outp = isT1 ? t1pad : scb;
#pragma unroll
  for (int n = 0; n < 4; n++) {
    int co2 = ntile * 128 + wn + n * 16 + fr;
    float bv = biasA[co2];
    int coL = isT1 ? co2 : (co2 - 256);
#pragma unroll
    for (int f = 0; f < 4; f++)
#pragma unroll
      for (int r = 0; r < 4; r++) {
        float v = acc[f][n][r] + bv;
        if (isT1) v = fmaxf(v, 0.0f);
        outp[ob[f * 4 + r] + coL] = (__bf16)v;
      }
  }
}

// ---------------- Kernel B: 3x3 conv on t1, + bias2 + scb, relu -> NCHW out -
// 1D grid 784 <= 1024 slots at 4 blocks/CU: single generation.
__global__ __launch_bounds__(256, 4) void convB_kernel(
    const __bf16* __restrict__ t1pad, const __bf16* __restrict__ w2f,
    const float* __restrict__ bias2, const __bf16* __restrict__ scb,
    float* __restrict__ out) {
  __shared__ alignas(16) __bf16 lA[2][128 * 64];
  const int tid = threadIdx.x;
  const int lane = tid & 63, wv = tid >> 6;
  const int u = blockIdx.x;
  const int mtile = (u >> 4) * 8 + (u & 7);   // 0..391
  const int ntile = (u >> 3) & 1;
  const int W = 36;

  const int lrow = lane >> 3;
  const int g = ((lane & 7) ^ lrow) * 8;
  int aoffs[4];
#pragma unroll
  for (int j = 0; j < 4; ++j) {
    int m = mtile * 128 + wv * 32 + j * 8 + lrow;
    int b = m / 3136, r = m % 3136, y = r / 56, x = r % 56;
    aoffs[j] = ((b * 58 + 1 + y) * 58 + (1 + x)) * 256 + g;
  }

  const int wm = (wv & 1) * 64, wn = (wv >> 1) * 64;
  const int fr = lane & 15, kh = lane >> 4;
  const int sw = fr & 7;
  const __bf16* bb = w2f + (ntile * 8 + (wv >> 1) * 4) * 4096 + lane * 8;

  f32x4 acc[4][4];
#pragma unroll
  for (int i = 0; i < 4; i++)
#pragma unroll
    for (int n = 0; n < 4; n++) acc[i][n] = (f32x4){0.f, 0.f, 0.f, 0.f};

  auto decode = [&](int w, int& adelta, int& btap, int& kc) {
    int tap = w >> 2;
    kc = w & 3;
    int ty = (tap >= 6) ? 2 : ((tap >= 3) ? 1 : 0);
    int tx = tap - ty * 3;
    adelta = ((ty - 1) * 58 + (tx - 1)) * 256;
    btap = tap * 65536;
  };
  auto stage = [&](int adelta, int kc, int buf) {
    __bf16* dst = &lA[buf][wv * 2048];
#pragma unroll
    for (int j = 0; j < 4; ++j)
      async_load16(t1pad + (aoffs[j] + adelta + kc * 64), dst + j * 512);
  };

  int adelta, btap, kc;
  decode(0, adelta, btap, kc);
  stage(adelta, kc, 0);
  __syncthreads();
  for (int w = 0; w < W; ++w) {
    const int buf = w & 1;
    const int cbtap = btap, ckc = kc;
    if (w + 1 < W) {
      decode(w + 1, adelta, btap, kc);
      stage(adelta, kc, buf ^ 1);
    }
    const __bf16* bp = bb + cbtap + ckc * 1024;
#pragma unroll
    for (int kk = 0; kk < 2; ++kk) {
      bf16x8 bfr[4], af[4];
#pragma unroll
      for (int n = 0; n < 4; ++n)
        bfr[n] = *(const bf16x8*)(bp + n * 4096 + kk * 512);
#pragma unroll
      for (int f = 0; f < 4; ++f)
        af[f] = *(const bf16x8*)(&lA[buf][(wm + f * 16 + fr) * 64 + (((kk * 4 + kh) ^ sw) * 8)]);
#pragma unroll
      for (int f = 0; f < 4; ++f)
#pragma unroll
        for (int n = 0; n < 4; ++n)
          acc[f][n] = __builtin_amdgcn_mfma_f32_16x16x32_bf16(af[f], bfr[n], acc[f][n], 0, 0, 0);
    }
    __syncthreads();
  }

  float bv[4];
#pragma unroll
  for (int n = 0; n < 4; ++n) bv[n] = bias2[ntile * 128 + wn + n * 16 + fr];
#pragma unroll
  for (int f = 0; f < 4; ++f) {
    int m0 = mtile * 128 + wm + f * 16 + kh * 4;
    int b = m0 / 3136, r0 = m0 % 3136;
#pragma unroll
    for (int n = 0; n < 4; ++n) {
      int co = ntile * 128 + wn + n * 16 + fr;
      const __bf16* scp = scb + (b * 3136 + r0) * 256 + co;
      f32x4 v;
#pragma unroll
      for (int r = 0; r < 4; ++r)
        v[r] = fmaxf(acc[f][n][r] + bv[n] + (float)scp[r * 256], 0.0f);
      *(f32x4*)(out + ((b * 256 + co) * 3136 + r0)) = v;
    }
  }
}

// ---------------- launch -----------------------------------------------------
extern "C" void kernel_launch(void* const* d_in, const int* in_sizes, int n_in,
                              void* d_out, int out_size, void* d_ws, size_t ws_size,
                              hipStream_t stream) {
  const float* x   = (const float*)d_in[0];
  const float* w1  = (const float*)d_in[1];
  const float* g1  = (const float*)d_in[2];
  const float* b1  = (const float*)d_in[3];
  const float* m1  = (const float*)d_in[4];
  const float* v1  = (const float*)d_in[5];
  const float* w2  = (const float*)d_in[6];
  const float* g2  = (const float*)d_in[7];
  const float* b2  = (const float*)d_in[8];
  const float* m2  = (const float*)d_in[9];
  const float* v2  = (const float*)d_in[10];
  const float* wsc = (const float*)d_in[11];
  const float* gs  = (const float*)d_in[12];
  const float* bs  = (const float*)d_in[13];
  const float* ms  = (const float*)d_in[14];
  const float* vs  = (const float*)d_in[15];
  float* out = (float*)d_out;

  char* ws = (char*)d_ws;
  __bf16* xpad  = (__bf16*)(ws);                  // 14,745,600 B
  __bf16* t1pad = (__bf16*)(ws + 14745600);       // 27,557,888 B
  __bf16* wbf   = (__bf16*)(ws + 42303488);       // 13,107,200 B
  __bf16* w2f   = (__bf16*)(ws + 55410688);       // 1,179,648 B
  __bf16* scb   = (__bf16*)(ws + 56590336);       // 25,690,112 B
  float* biasA  = (float*)(ws + 82280448);        // 2,048 B
  float* bias2  = (float*)(ws + 82282496);        // 1,024 B

  zero_kernel<<<dim3(10328), 256, 0, stream>>>((uint4*)ws, 2643968);
  prep_kernel<<<dim3(643), 256, 0, stream>>>(w1, g1, b1, m1, v1, wsc, gs, bs, ms, vs,
                                             w2, g2, b2, m2, v2, wbf, w2f, biasA, bias2);
  transpose_kernel<<<dim3(13, 8, 16), 256, 0, stream>>>(x, xpad);
  convA_kernel<<<dim3(1568), 256, 0, stream>>>(xpad, wbf, biasA, t1pad, scb);
  convB_kernel<<<dim3(784), 256, 0, stream>>>(t1pad, w2f, bias2, scb, out);
}